// Round 6
// baseline (7048730.469 us; speedup 1.0000x reference)
//
#include <hip/hip_runtime.h>
#include <hip/hip_bf16.h>

// BiLSTM-CRF loss, MI355X. B=64 T=512 V=30000 E=256 H=512 C=9.
// Round 6: XCD-local recurrence. Forward LSTM = 32 WGs claimed on XCD 0,
// backward = 32 WGs on XCD 1 (roles claimed via HW_REG_XCC_ID + atomic
// counters -> correctness independent of bid->XCD mapping). All h/flag
// exchange uses sc0-only ops (L1 bypass, shared XCD L2) -- no sc1, no
// die-level coherence-point round trips on the serial chain.

using short8 = __attribute__((ext_vector_type(8))) short;   // 8 x bf16 bits
using f32x4  = __attribute__((ext_vector_type(4))) float;
using i32x4  = __attribute__((ext_vector_type(4))) int;

#define TT 512
#define BB 64

__device__ __forceinline__ unsigned short f2bf(float f) {
  unsigned int u = __builtin_bit_cast(unsigned int, f);
  u += 0x7FFFu + ((u >> 16) & 1u);           // RNE
  return (unsigned short)(u >> 16);
}
__device__ __forceinline__ float bf2f(short s) {
  unsigned int u = ((unsigned int)(unsigned short)s) << 16;
  return __builtin_bit_cast(float, u);
}
__device__ __forceinline__ float fast_rcp(float x) { return __builtin_amdgcn_rcpf(x); }
__device__ __forceinline__ float sigmoid_f(float x) { return fast_rcp(1.f + __expf(-x)); }
__device__ __forceinline__ float tanh_f(float x) {
  float e = __expf(-2.f * fabsf(x));
  float r = (1.f - e) * fast_rcp(1.f + e);
  return copysignf(r, x);
}
#define SEL4(i, a0, a1, a2, a3) ((i)==0?(a0):((i)==1?(a1):((i)==2?(a2):(a3))))

// ---- XCD-L2 coherent ops: sc0 only (bypass L1, hit shared per-XCD L2) ----
__device__ __forceinline__ i32x4 load16_l2(const void* p) {      // no wait
  i32x4 r;
  asm volatile("global_load_dwordx4 %0, %1, off sc0" : "=v"(r) : "v"(p));
  return r;
}
__device__ __forceinline__ int load4_l2_wait(const void* p) {    // self-waiting
  int r;
  asm volatile("global_load_dword %0, %1, off sc0\n\ts_waitcnt vmcnt(0)"
               : "=v"(r) : "v"(p) : "memory");
  return r;
}
__device__ __forceinline__ void store16_l2(void* p, i32x4 v) {
  asm volatile("global_store_dwordx4 %0, %1, off sc0" :: "v"(p), "v"(v) : "memory");
}
#define WAITV(n) do { asm volatile("s_waitcnt vmcnt(" #n ")" ::: "memory"); \
                      __builtin_amdgcn_sched_barrier(0); } while (0)

// ---------------- K0a: pack LSTM + FC weights to bf16 -----------------------
// Slice widx = sl*2+d, col n in [0,64): gate g=n&3, jq=(n>>2)&3, tj=(n>>4)&1,
// nt=n>>5 -> unit jj = nt*8+jq*2+tj, weight row r = g*512 + sl*16 + jj.
__global__ void pack_weights(const float* __restrict__ Wih_f, const float* __restrict__ Whh_f,
                             const float* __restrict__ Wih_b, const float* __restrict__ Whh_b,
                             const float* __restrict__ Wfc,
                             short* __restrict__ WpackX, short* __restrict__ WpackH,
                             short* __restrict__ WfcPack) {
  const int bid = blockIdx.x;
  const int d = bid & 1, sl = bid >> 1;
  const float* Wih = d ? Wih_b : Wih_f;
  const float* Whh = d ? Whh_b : Whh_f;
  for (int idx = threadIdx.x; idx < 64 * 256; idx += 256) {
    int n = idx >> 8, k = idx & 255;
    int g = n & 3, jq = (n >> 2) & 3, tj = (n >> 4) & 1, nt = n >> 5;
    int r = g * 512 + sl * 16 + nt * 8 + jq * 2 + tj;
    WpackX[((size_t)bid * 64 + n) * 256 + k] = (short)f2bf(Wih[(size_t)r * 256 + k]);
  }
  for (int idx = threadIdx.x; idx < 64 * 512; idx += 256) {
    int n = idx >> 9, k = idx & 511;
    int g = n & 3, jq = (n >> 2) & 3, tj = (n >> 4) & 1, nt = n >> 5;
    int r = g * 512 + sl * 16 + nt * 8 + jq * 2 + tj;
    WpackH[((size_t)bid * 64 + n) * 512 + k] = (short)f2bf(Whh[(size_t)r * 512 + k]);
  }
  if (bid == 0) {
    for (int idx = threadIdx.x; idx < 16 * 1024; idx += 256) {
      int c = idx >> 10, k = idx & 1023;
      WfcPack[idx] = (c < 9) ? (short)f2bf(Wfc[c * 1024 + k]) : (short)0;
    }
  }
}

// ---------------- K0b: gather embeddings into MFMA A-fragment layout --------
__global__ void pack_x(const int* __restrict__ x, const float* __restrict__ emb,
                       short* __restrict__ xpack) {
  int gid = blockIdx.x * 256 + threadIdx.x;     // < 1048576
  int lane = gid & 63;
  int kc = (gid >> 6) & 7;
  int mt = (gid >> 9) & 3;
  int t  = gid >> 11;
  int b  = mt * 16 + (lane & 15);
  int k0 = kc * 32 + (lane >> 4) * 8;
  int vid = x[b * TT + t];
  const float* e = emb + (size_t)vid * 256 + k0;
  short8 v;
#pragma unroll
  for (int i = 0; i < 8; ++i) v[i] = (short)f2bf(e[i]);
  *reinterpret_cast<short8*>(xpack + (size_t)gid * 8) = v;
}

// ---------------- K0c: zero flags (256) + claim counters (8) ----------------
__global__ void init_state(int* __restrict__ flags) {
  int i = threadIdx.x;
  if (i < 264) flags[i] = 0;
}

// ---------------- K1: persistent XCD-local flag-synced BiLSTM ---------------
// 256 WGs launched; each reads HW_REG_XCC_ID and claims a role:
//   XCD 0 -> forward slices 0..31, XCD 1 -> backward slices 0..31, rest exit.
// All 256 WGs are co-resident (0 LDS except 16B, <=256 VGPR, 256 thr) so the
// 64 workers always run concurrently; placement affects speed only via which
// L2 they share -- correctness only needs "all fwd on one XCD, all bwd on one".
// Wave (mtb=wv&1, nt=wv>>1): rows [mtb*32,+32) x 8 units.
// flags[(d*2+mtb)*64 + g], g=sl*2+nt, dense dwords (lane polls flag[lane]).
__launch_bounds__(256, 1)
__global__ void lstm_step_kernel(const short8* __restrict__ xpack,
                                 const short* __restrict__ WpackX,
                                 const short* __restrict__ WpackH,
                                 short* __restrict__ hping,   // [2][2][64][512]
                                 int* __restrict__ flags,     // [4][64] + claims[8]
                                 short* __restrict__ hhist,   // [2][512][64][512]
                                 const float* __restrict__ b_f,
                                 const float* __restrict__ b_b,
                                 const int* __restrict__ seq_len) {
  __shared__ int role_sh;
  unsigned xcc;
  asm volatile("s_getreg_b32 %0, hwreg(HW_REG_XCC_ID)" : "=s"(xcc));
  if (threadIdx.x == 0) {
    int r = 1 << 20;
    if (xcc < 2) r = atomicAdd(&flags[256 + xcc], 1);   // claims after 256 flags
    role_sh = r;
  }
  __syncthreads();
  const int sl = role_sh;
  if (sl >= 32) return;                         // unneeded WG
  const int d = (int)xcc;                       // 0 = forward, 1 = backward
  const int widx = sl * 2 + d;                  // weight slice index

  const int tid = threadIdx.x;
  const int wv = tid >> 6;
  const int lane = tid & 63;
  const int l15 = lane & 15;
  const int lhi = lane >> 4;
  const int q = lane & 3;          // gate id of this lane's column
  const int jq = l15 >> 2;
  const int mtb = wv & 1;          // wave's row half
  const int nt = wv >> 1;          // wave's 8-unit group
  const int mbase = mtb * 32;
  const int nbase = nt * 32;
  const int ubase = sl * 16 + nt * 8;            // wave's 8-unit base

  // Wih + Whh B-fragments, register-resident for the whole kernel.
  short8 bfx[2][8];
#pragma unroll
  for (int tj = 0; tj < 2; ++tj)
#pragma unroll
    for (int kc = 0; kc < 8; ++kc)
      bfx[tj][kc] = *reinterpret_cast<const short8*>(
          WpackX + ((size_t)widx * 64 + nbase + tj * 16 + l15) * 256 + kc * 32 + lhi * 8);
  short8 bfh[2][16];
#pragma unroll
  for (int tj = 0; tj < 2; ++tj)
#pragma unroll
    for (int kc = 0; kc < 16; ++kc)
      bfh[tj][kc] = *reinterpret_cast<const short8*>(
          WpackH + ((size_t)widx * 64 + nbase + tj * 16 + l15) * 512 + kc * 32 + lhi * 8);

  const float* bias = d ? b_b : b_f;
  float bi[2], bfg[2], bgg[2], bog[2];
#pragma unroll
  for (int tj = 0; tj < 2; ++tj) {
    int jg = ubase + jq * 2 + tj;
    bi[tj]  = bias[jg];
    bfg[tj] = bias[512 + jg];
    bgg[tj] = bias[1024 + jg];
    bog[tj] = bias[1536 + jg];
  }
  int brow[2], Lr[2];
#pragma unroll
  for (int ti = 0; ti < 2; ++ti) {
    brow[ti] = mbase + ti * 16 + lhi * 4 + q;   // this lane's batch row
    Lr[ti] = seq_len[brow[ti]];
  }
  float cst[2][2] = {{0.f, 0.f}, {0.f, 0.f}};
  float hst[2][2] = {{0.f, 0.f}, {0.f, 0.f}};

  int* fl_grp  = flags + (d * 2 + mtb) * 64;
  int* fl_mine = fl_grp + (sl * 2 + nt);
  const int* fl_poll = fl_grp + lane;           // lane polls one flag

  for (int s = 0; s < TT; ++s) {
    const int t = d ? (TT - 1 - s) : s;
    f32x4 acc[2][2];
#pragma unroll
    for (int ti = 0; ti < 2; ++ti)
#pragma unroll
      for (int tj = 0; tj < 2; ++tj) acc[ti][tj] = (f32x4){0.f, 0.f, 0.f, 0.f};

    // ---- Phase A: x@Wih^T (no sequential dependency) ----
    const short8* xp = xpack + (size_t)t * 2048;
#pragma unroll
    for (int kc = 0; kc < 8; ++kc) {
      short8 af[2];
#pragma unroll
      for (int ti = 0; ti < 2; ++ti)
        af[ti] = xp[((mtb * 2 + ti) * 8 + kc) * 64 + lane];
#pragma unroll
      for (int ti = 0; ti < 2; ++ti)
#pragma unroll
        for (int tj = 0; tj < 2; ++tj)
          acc[ti][tj] = __builtin_amdgcn_mfma_f32_16x16x32_bf16(af[ti], bfx[tj][kc], acc[ti][tj], 0, 0, 0);
    }

    if (s > 0) {
      // ---- Phase B: poll 64 producer flags of my (dir,row-half) group ----
      {
        int vtries = 0;
        while (true) {
          int f = load4_l2_wait(fl_poll);
          if (__all(f >= s)) break;
          __builtin_amdgcn_s_sleep(1);
          if (++vtries > (1 << 17)) break;     // anti-hang valve
        }
      }
      __builtin_amdgcn_sched_barrier(0);

      // ---- Phase C: issue all 32 h-loads (L2-local), counted-vmcnt MFMA ----
      const short* hp = hping + ((size_t)(d * 2 + (s & 1)) * 64) * 512;
      i32x4 hbuf[32];
#pragma unroll
      for (int kc = 0; kc < 16; ++kc)
#pragma unroll
        for (int ti = 0; ti < 2; ++ti)
          hbuf[kc * 2 + ti] =
              load16_l2(hp + (mbase + ti * 16 + l15) * 512 + kc * 32 + lhi * 8);
      WAITV(16);                                // first 16 loads (kc 0..7) done
#pragma unroll
      for (int kc = 0; kc < 8; ++kc)
#pragma unroll
        for (int ti = 0; ti < 2; ++ti) {
          short8 a = __builtin_bit_cast(short8, hbuf[kc * 2 + ti]);
#pragma unroll
          for (int tj = 0; tj < 2; ++tj)
            acc[ti][tj] = __builtin_amdgcn_mfma_f32_16x16x32_bf16(a, bfh[tj][kc], acc[ti][tj], 0, 0, 0);
        }
      WAITV(0);                                 // remaining 16 loads done
#pragma unroll
      for (int kc = 8; kc < 16; ++kc)
#pragma unroll
        for (int ti = 0; ti < 2; ++ti) {
          short8 a = __builtin_bit_cast(short8, hbuf[kc * 2 + ti]);
#pragma unroll
          for (int tj = 0; tj < 2; ++tj)
            acc[ti][tj] = __builtin_amdgcn_mfma_f32_16x16x32_bf16(a, bfh[tj][kc], acc[ti][tj], 0, 0, 0);
        }
    }

    // ---- Phase D: gates via 4-lane shuffles, state update, 16B stores ----
    short* hpo = hping + ((size_t)(d * 2 + ((s + 1) & 1)) * 64) * 512;
    unsigned int pk[2][4];
#pragma unroll
    for (int ti = 0; ti < 2; ++ti) {
      bool m = (t < Lr[ti]);
      unsigned short hnb[2], htb[2];
#pragma unroll
      for (int tj = 0; tj < 2; ++tj) {
        f32x4 A = acc[ti][tj];
        float a0 = A[0], a1 = A[1], a2 = A[2], a3 = A[3];
        float e10 = __shfl_xor(a0, 1, 64), e11 = __shfl_xor(a1, 1, 64),
              e12 = __shfl_xor(a2, 1, 64), e13 = __shfl_xor(a3, 1, 64);
        float e20 = __shfl_xor(a0, 2, 64), e21 = __shfl_xor(a1, 2, 64),
              e22 = __shfl_xor(a2, 2, 64), e23 = __shfl_xor(a3, 2, 64);
        float e30 = __shfl_xor(a0, 3, 64), e31 = __shfl_xor(a1, 3, 64),
              e32 = __shfl_xor(a2, 3, 64), e33 = __shfl_xor(a3, 3, 64);
        float g0 = SEL4(q, a0, a1, a2, a3);
        float g1 = SEL4(q, e10, e11, e12, e13);
        float g2 = SEL4(q, e20, e21, e22, e23);
        float g3 = SEL4(q, e30, e31, e32, e33);
        float gi = SEL4(q,     g0, g1, g2, g3) + bi[tj];
        float gf = SEL4(q ^ 1, g0, g1, g2, g3) + bfg[tj];
        float gg = SEL4(q ^ 2, g0, g1, g2, g3) + bgg[tj];
        float go = SEL4(q ^ 3, g0, g1, g2, g3) + bog[tj];
        float si = sigmoid_f(gi), sf = sigmoid_f(gf), so = sigmoid_f(go);
        float ct = sf * cst[ti][tj] + si * tanh_f(gg);
        float ht = so * tanh_f(ct);
        float cn = m ? ct : cst[ti][tj];
        float hn = m ? ht : hst[ti][tj];
        cst[ti][tj] = cn;
        hst[ti][tj] = hn;
        hnb[tj] = f2bf(hn);
        htb[tj] = m ? f2bf(ht) : (unsigned short)0;
      }
      unsigned int up = ((unsigned int)hnb[1] << 16) | hnb[0];
      unsigned int uh = ((unsigned int)htb[1] << 16) | htb[0];
      // gather the row's 4 unit-pairs (jq=0..3 at lanes +4,+8,+12) into jq==0
      unsigned int p1 = __shfl_xor(up, 4, 64), p2 = __shfl_xor(up, 8, 64),
                   p3 = __shfl_xor(up, 12, 64);
      unsigned int q1 = __shfl_xor(uh, 4, 64), q2 = __shfl_xor(uh, 8, 64),
                   q3 = __shfl_xor(uh, 12, 64);
      if (jq == 0) {
        i32x4 packp = {(int)up, (int)p1, (int)p2, (int)p3};
        store16_l2(hpo + brow[ti] * 512 + ubase, packp);
      }
      pk[ti][0] = uh; pk[ti][1] = q1; pk[ti][2] = q2; pk[ti][3] = q3;
    }

    // ---- Phase E: ack own h-stores (at L2), publish flag ----
    if (lane == 0) {
      int sv = s + 1;
      asm volatile("s_waitcnt vmcnt(0)\n\t"
                   "global_store_dword %0, %1, off sc0"
                   :: "v"(fl_mine), "v"(sv) : "memory");
    }

    // ---- Phase F: masked history, off the critical path (cached stores) ----
#pragma unroll
    for (int ti = 0; ti < 2; ++ti)
      if (jq == 0) {
        i32x4 ph = {(int)pk[ti][0], (int)pk[ti][1], (int)pk[ti][2], (int)pk[ti][3]};
        *reinterpret_cast<i32x4*>(
            &hhist[(((size_t)d * TT + t) * 64 + brow[ti]) * 512 + ubase]) = ph;
      }
  }
}

// ---------------- K2: emission logits = [hf|hb] @ Wfc^T via MFMA ------------
__launch_bounds__(256)
__global__ void emis_kernel(const short* __restrict__ hhist,
                            const short* __restrict__ WfcPack,
                            float* __restrict__ logits) {
  __shared__ short wfc[16 * 1032];             // padded stride vs bank conflicts
  const int tid = threadIdx.x;
  for (int idx = tid; idx < 2048; idx += 256) {
    int n = idx >> 7, c8 = idx & 127;
    short8 v = *reinterpret_cast<const short8*>(WfcPack + n * 1024 + c8 * 8);
    *reinterpret_cast<short8*>(&wfc[n * 1032 + c8 * 8]) = v;
  }
  __syncthreads();
  const int wv = tid >> 6, lane = tid & 63;
  const int l15 = lane & 15, lhi = lane >> 4;
#pragma unroll
  for (int mt2 = 0; mt2 < 2; ++mt2) {
    int m = (blockIdx.x * 4 + wv) * 2 + mt2;
    int r0 = m * 16;
    f32x4 acc = (f32x4){0.f, 0.f, 0.f, 0.f};
#pragma unroll
    for (int kc = 0; kc < 32; ++kc) {
      const short* pa = hhist + ((kc < 16) ? 0 : (size_t)16777216)
                        + (size_t)(r0 + l15) * 512 + (kc & 15) * 32 + lhi * 8;
      short8 a = *reinterpret_cast<const short8*>(pa);
      short8 b = *reinterpret_cast<const short8*>(&wfc[l15 * 1032 + kc * 32 + lhi * 8]);
      acc = __builtin_amdgcn_mfma_f32_16x16x32_bf16(a, b, acc, 0, 0, 0);
    }
    int c = l15;
    if (c < 9) {
#pragma unroll
      for (int reg = 0; reg < 4; ++reg) {
        int rr = r0 + lhi * 4 + reg;
        int b = rr & 63, t = rr >> 6;
        logits[((size_t)b * TT + t) * 9 + c] = acc[reg];
      }
    }
  }
}

// ---------------- K3: CRF numerator + forward algorithm per batch -----------
__global__ void crf_kernel(const float* __restrict__ logits, const int* __restrict__ y,
                           const int* __restrict__ seq_len, const float* __restrict__ start_t,
                           const float* __restrict__ end_t, const float* __restrict__ trans,
                           float* __restrict__ partials) {
  const int b = blockIdx.x;
  const int lane = threadIdx.x;          // 64
  const float* lg = logits + (size_t)b * TT * 9;
  const int* yb = y + b * TT;
  const int L = seq_len[b];

  float acc = 0.f;
  for (int t = lane; t < TT; t += 64) {
    if (t < L) {
      float mx = lg[t * 9];
      for (int c = 1; c < 9; ++c) mx = fmaxf(mx, lg[t * 9 + c]);
      float se = 0.f;
      for (int c = 0; c < 9; ++c) se += __expf(lg[t * 9 + c] - mx);
      float lse = mx + __logf(se);
      int yt = yb[t];
      acc += lg[t * 9 + yt] - lse;
      if (t >= 1) acc += trans[yb[t - 1] * 9 + yt];
    }
  }
#pragma unroll
  for (int off = 32; off >= 1; off >>= 1) acc += __shfl_down(acc, off, 64);

  const int c = (lane < 9) ? lane : 0;
  float score;
  {
    float mx = lg[0];
    for (int cc = 1; cc < 9; ++cc) mx = fmaxf(mx, lg[cc]);
    float se = 0.f;
    for (int cc = 0; cc < 9; ++cc) se += __expf(lg[cc] - mx);
    score = start_t[c] + lg[c] - (mx + __logf(se));
  }
  float tr[9];
#pragma unroll
  for (int cc = 0; cc < 9; ++cc) tr[cc] = trans[cc * 9 + c];
  for (int t = 1; t < L; ++t) {
    const float* lt = lg + t * 9;
    float mx2 = lt[0];
    for (int cc = 1; cc < 9; ++cc) mx2 = fmaxf(mx2, lt[cc]);
    float se2 = 0.f;
    for (int cc = 0; cc < 9; ++cc) se2 += __expf(lt[cc] - mx2);
    float em = lt[c] - (mx2 + __logf(se2));
    float vv[9];
    float mx = -1e30f;
#pragma unroll
    for (int cc = 0; cc < 9; ++cc) {
      float sp = __shfl(score, cc, 64);
      vv[cc] = sp + tr[cc];
      mx = fmaxf(mx, vv[cc]);
    }
    float se = 0.f;
#pragma unroll
    for (int cc = 0; cc < 9; ++cc) se += __expf(vv[cc] - mx);
    score = mx + __logf(se) + em;
  }
  float val = (lane < 9) ? (score + end_t[lane]) : -1e30f;
  float mm = val;
#pragma unroll
  for (int off = 1; off < 64; off <<= 1) mm = fmaxf(mm, __shfl_xor(mm, off, 64));
  float se = (lane < 9) ? __expf(val - mm) : 0.f;
#pragma unroll
  for (int off = 1; off < 64; off <<= 1) se += __shfl_xor(se, off, 64);
  float den = mm + __logf(se);
  if (lane == 0) {
    float num = acc + start_t[yb[0]] + end_t[yb[L - 1]];
    partials[b] = num - den;
  }
}

// ---------------- K4: final reduce ------------------------------------------
__global__ void finalize_kernel(const float* __restrict__ partials, float* __restrict__ out) {
  int l = threadIdx.x;
  float v = partials[l];
#pragma unroll
  for (int off = 32; off >= 1; off >>= 1) v += __shfl_down(v, off, 64);
  if (l == 0) out[0] = -v;
}

extern "C" void kernel_launch(void* const* d_in, const int* in_sizes, int n_in,
                              void* d_out, int out_size, void* d_ws, size_t ws_size,
                              hipStream_t stream) {
  const int*   x     = (const int*)d_in[0];
  const int*   seqln = (const int*)d_in[1];
  const int*   y     = (const int*)d_in[2];
  const float* emb   = (const float*)d_in[3];
  const float* Wih_f = (const float*)d_in[4];
  const float* Whh_f = (const float*)d_in[5];
  const float* b_f   = (const float*)d_in[6];
  const float* Wih_b = (const float*)d_in[7];
  const float* Whh_b = (const float*)d_in[8];
  const float* b_b   = (const float*)d_in[9];
  const float* Wfc   = (const float*)d_in[10];
  const float* st    = (const float*)d_in[11];
  const float* en    = (const float*)d_in[12];
  const float* trans = (const float*)d_in[13];
  float* out = (float*)d_out;

  char* ws = (char*)d_ws;                         // total required ~91.7 MB
  short* WpackX   = (short*)(ws + 0);             // 2,097,152
  short* WpackH   = (short*)(ws + 2097152);       // 4,194,304
  short* WfcPack  = (short*)(ws + 6291456);       //    32,768
  short* xpack    = (short*)(ws + 6324224);       // 16,777,216
  short* hping    = (short*)(ws + 23101440);      //   262,144
  int*   flags    = (int*)  (ws + 23363584);      //     1,056 (256 flags + 8 claims)
  float* partials = (float*)(ws + 23364640);      //       256
  float* logits   = (float*)(ws + 23364896);      // 1,179,648
  short* hhist    = (short*)(ws + 24544544);      // 67,108,864 -> end 91,653,408

  pack_weights<<<64, 256, 0, stream>>>(Wih_f, Whh_f, Wih_b, Whh_b, Wfc,
                                       WpackX, WpackH, WfcPack);
  pack_x<<<4096, 256, 0, stream>>>(x, emb, xpack);
  init_state<<<1, 512, 0, stream>>>(flags);
  lstm_step_kernel<<<256, 256, 0, stream>>>((const short8*)xpack, WpackX, WpackH,
                                            hping, flags, hhist, b_f, b_b, seqln);
  emis_kernel<<<256, 256, 0, stream>>>(hhist, WfcPack, logits);
  crf_kernel<<<64, 64, 0, stream>>>(logits, y, seqln, st, en, trans, partials);
  finalize_kernel<<<1, 64, 0, stream>>>(partials, out);
}

// Round 7
// 4691.592 us; speedup vs baseline: 1502.4177x; 1502.4177x over previous
//
#include <hip/hip_runtime.h>
#include <hip/hip_bf16.h>

// BiLSTM-CRF loss, MI355X. B=64 T=512 V=30000 E=256 H=512 C=9.
// Round 7: write-once per-step exchange buffer hexch[d][t][64][512] (sc0sc1
// 16B gathered stores + vmcnt-ack + dense sc0sc1 flags), consumers read h
// with PLAIN CACHED loads (safe: address written once, read only after flag
// handshake; per-XCD L2 multicasts the tile). hexch doubles as the history
// for the emission GEMM (CRF ignores t>=L, so frozen-carry values are fine).

using short8 = __attribute__((ext_vector_type(8))) short;   // 8 x bf16 bits
using f32x4  = __attribute__((ext_vector_type(4))) float;
using i32x4  = __attribute__((ext_vector_type(4))) int;

#define TT 512
#define BB 64

__device__ __forceinline__ unsigned short f2bf(float f) {
  unsigned int u = __builtin_bit_cast(unsigned int, f);
  u += 0x7FFFu + ((u >> 16) & 1u);           // RNE
  return (unsigned short)(u >> 16);
}
__device__ __forceinline__ float bf2f(short s) {
  unsigned int u = ((unsigned int)(unsigned short)s) << 16;
  return __builtin_bit_cast(float, u);
}
__device__ __forceinline__ float fast_rcp(float x) { return __builtin_amdgcn_rcpf(x); }
__device__ __forceinline__ float sigmoid_f(float x) { return fast_rcp(1.f + __expf(-x)); }
__device__ __forceinline__ float tanh_f(float x) {
  float e = __expf(-2.f * fabsf(x));
  float r = (1.f - e) * fast_rcp(1.f + e);
  return copysignf(r, x);
}
#define SEL4(i, a0, a1, a2, a3) ((i)==0?(a0):((i)==1?(a1):((i)==2?(a2):(a3))))

// ---- coherence-point ops (sc0 sc1): for flags + h publication ----
__device__ __forceinline__ i32x4 load16_sc_wait(const void* p) { // self-waiting
  i32x4 r;
  asm volatile("global_load_dwordx4 %0, %1, off sc0 sc1\n\ts_waitcnt vmcnt(0)"
               : "=v"(r) : "v"(p) : "memory");
  return r;
}
__device__ __forceinline__ void store16_sc(void* p, i32x4 v) {
  asm volatile("global_store_dwordx4 %0, %1, off sc0 sc1" :: "v"(p), "v"(v) : "memory");
}
// ---- cached load (L2-multicast path for the h tile), manual vmcnt ----
__device__ __forceinline__ i32x4 load16_ca(const void* p) {      // no wait
  i32x4 r;
  asm volatile("global_load_dwordx4 %0, %1, off" : "=v"(r) : "v"(p));
  return r;
}
#define WAITV(n) do { asm volatile("s_waitcnt vmcnt(" #n ")" ::: "memory"); \
                      __builtin_amdgcn_sched_barrier(0); } while (0)

// ---------------- K0a: pack LSTM + FC weights to bf16 -----------------------
// LSTM col n in [0,64) of block bid (d=bid&1, sl=bid>>1):
//   gate g=n&3, jq=(n>>2)&3, tj=(n>>4)&1, nt=n>>5 -> unit jj = nt*8+jq*2+tj,
//   weight row r = g*512 + sl*16 + jj.  (unit permutation enables wide stores)
__global__ void pack_weights(const float* __restrict__ Wih_f, const float* __restrict__ Whh_f,
                             const float* __restrict__ Wih_b, const float* __restrict__ Whh_b,
                             const float* __restrict__ Wfc,
                             short* __restrict__ WpackX, short* __restrict__ WpackH,
                             short* __restrict__ WfcPack) {
  const int bid = blockIdx.x;
  const int d = bid & 1, sl = bid >> 1;
  const float* Wih = d ? Wih_b : Wih_f;
  const float* Whh = d ? Whh_b : Whh_f;
  for (int idx = threadIdx.x; idx < 64 * 256; idx += 256) {
    int n = idx >> 8, k = idx & 255;
    int g = n & 3, jq = (n >> 2) & 3, tj = (n >> 4) & 1, nt = n >> 5;
    int r = g * 512 + sl * 16 + nt * 8 + jq * 2 + tj;
    WpackX[((size_t)bid * 64 + n) * 256 + k] = (short)f2bf(Wih[(size_t)r * 256 + k]);
  }
  for (int idx = threadIdx.x; idx < 64 * 512; idx += 256) {
    int n = idx >> 9, k = idx & 511;
    int g = n & 3, jq = (n >> 2) & 3, tj = (n >> 4) & 1, nt = n >> 5;
    int r = g * 512 + sl * 16 + nt * 8 + jq * 2 + tj;
    WpackH[((size_t)bid * 64 + n) * 512 + k] = (short)f2bf(Whh[(size_t)r * 512 + k]);
  }
  if (bid == 0) {
    for (int idx = threadIdx.x; idx < 16 * 1024; idx += 256) {
      int c = idx >> 10, k = idx & 1023;
      WfcPack[idx] = (c < 9) ? (short)f2bf(Wfc[c * 1024 + k]) : (short)0;
    }
  }
}

// ---------------- K0b: gather embeddings into MFMA A-fragment layout --------
__global__ void pack_x(const int* __restrict__ x, const float* __restrict__ emb,
                       short* __restrict__ xpack) {
  int gid = blockIdx.x * 256 + threadIdx.x;     // < 1048576
  int lane = gid & 63;
  int kc = (gid >> 6) & 7;
  int mt = (gid >> 9) & 3;
  int t  = gid >> 11;
  int b  = mt * 16 + (lane & 15);
  int k0 = kc * 32 + (lane >> 4) * 8;
  int vid = x[b * TT + t];
  const float* e = emb + (size_t)vid * 256 + k0;
  short8 v;
#pragma unroll
  for (int i = 0; i < 8; ++i) v[i] = (short)f2bf(e[i]);
  *reinterpret_cast<short8*>(xpack + (size_t)gid * 8) = v;
}

// ---------------- K0c: zero flags -------------------------------------------
__global__ void init_state(int* __restrict__ flags) {
  flags[threadIdx.x] = 0;                       // 256 flags
}

// ---------------- K1: persistent flag-synced BiLSTM -------------------------
// 64 WGs x 256 thr. WG: d=bid&1, sl=bid>>1 owns 16 units x 4 gates.
// Wave (mtb=wv&1, nt=wv>>1): rows [mtb*32,+32) x 8 units.
// flags[(d*2+mtb)*64 + g], g=sl*2+nt, dense dwords, sc0sc1.
// Per step: x-MFMA (regs) -> packed-quad sc poll of 64 flags -> issue all 32
// CACHED h-loads from hexch[d][t_prev] (write-once addresses => safe; L2
// multicast) -> counted-vmcnt MFMA -> gates/state -> gathered 16B sc0sc1
// store of frozen h into hexch[d][t] -> vmcnt ack -> flag publish.
__launch_bounds__(256, 1)
__global__ void lstm_step_kernel(const short8* __restrict__ xpack,
                                 const short* __restrict__ WpackX,
                                 const short* __restrict__ WpackH,
                                 short* __restrict__ hexch,   // [2][512][64][512]
                                 int* __restrict__ flags,     // [4][64]
                                 const float* __restrict__ b_f,
                                 const float* __restrict__ b_b,
                                 const int* __restrict__ seq_len) {
  const int bid = blockIdx.x;
  const int d = bid & 1;
  const int sl = bid >> 1;
  const int tid = threadIdx.x;
  const int wv = tid >> 6;
  const int lane = tid & 63;
  const int l15 = lane & 15;
  const int lhi = lane >> 4;
  const int q = lane & 3;          // gate id of this lane's column
  const int jq = l15 >> 2;
  const int mtb = wv & 1;          // wave's row half
  const int nt = wv >> 1;          // wave's 8-unit group
  const int mbase = mtb * 32;
  const int nbase = nt * 32;
  const int ubase = sl * 16 + nt * 8;            // wave's 8-unit base

  // Wih + Whh B-fragments, register-resident for the whole kernel.
  short8 bfx[2][8];
#pragma unroll
  for (int tj = 0; tj < 2; ++tj)
#pragma unroll
    for (int kc = 0; kc < 8; ++kc)
      bfx[tj][kc] = *reinterpret_cast<const short8*>(
          WpackX + ((size_t)bid * 64 + nbase + tj * 16 + l15) * 256 + kc * 32 + lhi * 8);
  short8 bfh[2][16];
#pragma unroll
  for (int tj = 0; tj < 2; ++tj)
#pragma unroll
    for (int kc = 0; kc < 16; ++kc)
      bfh[tj][kc] = *reinterpret_cast<const short8*>(
          WpackH + ((size_t)bid * 64 + nbase + tj * 16 + l15) * 512 + kc * 32 + lhi * 8);

  const float* bias = d ? b_b : b_f;
  float bi[2], bfg[2], bgg[2], bog[2];
#pragma unroll
  for (int tj = 0; tj < 2; ++tj) {
    int jg = ubase + jq * 2 + tj;
    bi[tj]  = bias[jg];
    bfg[tj] = bias[512 + jg];
    bgg[tj] = bias[1024 + jg];
    bog[tj] = bias[1536 + jg];
  }
  int brow[2], Lr[2];
#pragma unroll
  for (int ti = 0; ti < 2; ++ti) {
    brow[ti] = mbase + ti * 16 + lhi * 4 + q;   // this lane's batch row
    Lr[ti] = seq_len[brow[ti]];
  }
  float cst[2][2] = {{0.f, 0.f}, {0.f, 0.f}};
  float hst[2][2] = {{0.f, 0.f}, {0.f, 0.f}};

  int* fl_grp  = flags + (d * 2 + mtb) * 64;
  int* fl_mine = fl_grp + (sl * 2 + nt);
  const int* fl_quad = fl_grp + (lane & 15) * 4;   // packed dwordx4 poll

  for (int s = 0; s < TT; ++s) {
    const int t = d ? (TT - 1 - s) : s;
    f32x4 acc[2][2];
#pragma unroll
    for (int ti = 0; ti < 2; ++ti)
#pragma unroll
      for (int tj = 0; tj < 2; ++tj) acc[ti][tj] = (f32x4){0.f, 0.f, 0.f, 0.f};

    // ---- Phase A: x@Wih^T (no sequential dependency; overlaps poll tail) ---
    const short8* xp = xpack + (size_t)t * 2048;
#pragma unroll
    for (int kc = 0; kc < 8; ++kc) {
      short8 af[2];
#pragma unroll
      for (int ti = 0; ti < 2; ++ti)
        af[ti] = xp[((mtb * 2 + ti) * 8 + kc) * 64 + lane];
#pragma unroll
      for (int ti = 0; ti < 2; ++ti)
#pragma unroll
        for (int tj = 0; tj < 2; ++tj)
          acc[ti][tj] = __builtin_amdgcn_mfma_f32_16x16x32_bf16(af[ti], bfx[tj][kc], acc[ti][tj], 0, 0, 0);
    }

    if (s > 0) {
      // ---- Phase B: poll the 64 producer flags (dwordx4 over dense flags) --
      {
        int vtries = 0;
        while (true) {
          i32x4 f = load16_sc_wait(fl_quad);
          bool ok = (f[0] >= s) & (f[1] >= s) & (f[2] >= s) & (f[3] >= s);
          if (__all(ok)) break;
          __builtin_amdgcn_s_sleep(1);
          if (++vtries > (1 << 18)) break;     // anti-hang valve
        }
      }
      __builtin_amdgcn_sched_barrier(0);

      // ---- Phase C: 32 CACHED h-loads from write-once hexch[d][t_prev] ----
      const int tprev = d ? (t + 1) : (t - 1);
      const short* hp = hexch + ((size_t)d * TT + tprev) * (64 * 512);
      i32x4 hbuf[32];
#pragma unroll
      for (int kc = 0; kc < 16; ++kc)
#pragma unroll
        for (int ti = 0; ti < 2; ++ti)
          hbuf[kc * 2 + ti] =
              load16_ca(hp + (mbase + ti * 16 + l15) * 512 + kc * 32 + lhi * 8);
      WAITV(16);                                // first 16 loads (kc 0..7) done
#pragma unroll
      for (int kc = 0; kc < 8; ++kc)
#pragma unroll
        for (int ti = 0; ti < 2; ++ti) {
          short8 a = __builtin_bit_cast(short8, hbuf[kc * 2 + ti]);
#pragma unroll
          for (int tj = 0; tj < 2; ++tj)
            acc[ti][tj] = __builtin_amdgcn_mfma_f32_16x16x32_bf16(a, bfh[tj][kc], acc[ti][tj], 0, 0, 0);
        }
      WAITV(0);                                 // remaining 16 loads done
#pragma unroll
      for (int kc = 8; kc < 16; ++kc)
#pragma unroll
        for (int ti = 0; ti < 2; ++ti) {
          short8 a = __builtin_bit_cast(short8, hbuf[kc * 2 + ti]);
#pragma unroll
          for (int tj = 0; tj < 2; ++tj)
            acc[ti][tj] = __builtin_amdgcn_mfma_f32_16x16x32_bf16(a, bfh[tj][kc], acc[ti][tj], 0, 0, 0);
        }
    }

    // ---- Phase D: gates via 4-lane shuffles, state update, 16B sc stores ---
    short* hx = hexch + ((size_t)d * TT + t) * (64 * 512);
#pragma unroll
    for (int ti = 0; ti < 2; ++ti) {
      bool m = (t < Lr[ti]);
      unsigned short hnb[2];
#pragma unroll
      for (int tj = 0; tj < 2; ++tj) {
        f32x4 A = acc[ti][tj];
        float a0 = A[0], a1 = A[1], a2 = A[2], a3 = A[3];
        float e10 = __shfl_xor(a0, 1, 64), e11 = __shfl_xor(a1, 1, 64),
              e12 = __shfl_xor(a2, 1, 64), e13 = __shfl_xor(a3, 1, 64);
        float e20 = __shfl_xor(a0, 2, 64), e21 = __shfl_xor(a1, 2, 64),
              e22 = __shfl_xor(a2, 2, 64), e23 = __shfl_xor(a3, 2, 64);
        float e30 = __shfl_xor(a0, 3, 64), e31 = __shfl_xor(a1, 3, 64),
              e32 = __shfl_xor(a2, 3, 64), e33 = __shfl_xor(a3, 3, 64);
        float g0 = SEL4(q, a0, a1, a2, a3);
        float g1 = SEL4(q, e10, e11, e12, e13);
        float g2 = SEL4(q, e20, e21, e22, e23);
        float g3 = SEL4(q, e30, e31, e32, e33);
        float gi = SEL4(q,     g0, g1, g2, g3) + bi[tj];
        float gf = SEL4(q ^ 1, g0, g1, g2, g3) + bfg[tj];
        float gg = SEL4(q ^ 2, g0, g1, g2, g3) + bgg[tj];
        float go = SEL4(q ^ 3, g0, g1, g2, g3) + bog[tj];
        float si = sigmoid_f(gi), sf = sigmoid_f(gf), so = sigmoid_f(go);
        float ct = sf * cst[ti][tj] + si * tanh_f(gg);
        float ht = so * tanh_f(ct);
        float cn = m ? ct : cst[ti][tj];
        float hn = m ? ht : hst[ti][tj];
        cst[ti][tj] = cn;
        hst[ti][tj] = hn;
        hnb[tj] = f2bf(hn);                     // frozen carry (= history when t<L)
      }
      unsigned int up = ((unsigned int)hnb[1] << 16) | hnb[0];
      // gather the row's 4 unit-pairs (jq=0..3 at lanes +4,+8,+12) into jq==0
      unsigned int p1 = __shfl_xor(up, 4, 64), p2 = __shfl_xor(up, 8, 64),
                   p3 = __shfl_xor(up, 12, 64);
      if (jq == 0) {
        i32x4 packp = {(int)up, (int)p1, (int)p2, (int)p3};
        store16_sc(hx + brow[ti] * 512 + ubase, packp);
      }
    }

    // ---- Phase E: ack own h-stores at the coherence point, publish flag ----
    if (lane == 0) {
      int sv = s + 1;
      asm volatile("s_waitcnt vmcnt(0)\n\t"
                   "global_store_dword %0, %1, off sc0 sc1"
                   :: "v"(fl_mine), "v"(sv) : "memory");
    }
  }
}

// ---------------- K2: emission logits = [hf|hb] @ Wfc^T via MFMA ------------
// Reads hexch directly (frozen values at t>=L are irrelevant: CRF masks them).
__launch_bounds__(256)
__global__ void emis_kernel(const short* __restrict__ hexch,
                            const short* __restrict__ WfcPack,
                            float* __restrict__ logits) {
  __shared__ short wfc[16 * 1032];             // padded stride vs bank conflicts
  const int tid = threadIdx.x;
  for (int idx = tid; idx < 2048; idx += 256) {
    int n = idx >> 7, c8 = idx & 127;
    short8 v = *reinterpret_cast<const short8*>(WfcPack + n * 1024 + c8 * 8);
    *reinterpret_cast<short8*>(&wfc[n * 1032 + c8 * 8]) = v;
  }
  __syncthreads();
  const int wv = tid >> 6, lane = tid & 63;
  const int l15 = lane & 15, lhi = lane >> 4;
#pragma unroll
  for (int mt2 = 0; mt2 < 2; ++mt2) {
    int m = (blockIdx.x * 4 + wv) * 2 + mt2;
    int r0 = m * 16;                           // r = t*64 + b
    f32x4 acc = (f32x4){0.f, 0.f, 0.f, 0.f};
#pragma unroll
    for (int kc = 0; kc < 32; ++kc) {
      const short* pa = hexch + ((kc < 16) ? 0 : (size_t)16777216)
                        + (size_t)(r0 + l15) * 512 + (kc & 15) * 32 + lhi * 8;
      short8 a = *reinterpret_cast<const short8*>(pa);
      short8 b = *reinterpret_cast<const short8*>(&wfc[l15 * 1032 + kc * 32 + lhi * 8]);
      acc = __builtin_amdgcn_mfma_f32_16x16x32_bf16(a, b, acc, 0, 0, 0);
    }
    int c = l15;
    if (c < 9) {
#pragma unroll
      for (int reg = 0; reg < 4; ++reg) {
        int rr = r0 + lhi * 4 + reg;
        int b = rr & 63, t = rr >> 6;
        logits[((size_t)b * TT + t) * 9 + c] = acc[reg];
      }
    }
  }
}

// ---------------- K3: CRF numerator + forward algorithm per batch -----------
__global__ void crf_kernel(const float* __restrict__ logits, const int* __restrict__ y,
                           const int* __restrict__ seq_len, const float* __restrict__ start_t,
                           const float* __restrict__ end_t, const float* __restrict__ trans,
                           float* __restrict__ partials) {
  const int b = blockIdx.x;
  const int lane = threadIdx.x;          // 64
  const float* lg = logits + (size_t)b * TT * 9;
  const int* yb = y + b * TT;
  const int L = seq_len[b];

  float acc = 0.f;
  for (int t = lane; t < TT; t += 64) {
    if (t < L) {
      float mx = lg[t * 9];
      for (int c = 1; c < 9; ++c) mx = fmaxf(mx, lg[t * 9 + c]);
      float se = 0.f;
      for (int c = 0; c < 9; ++c) se += __expf(lg[t * 9 + c] - mx);
      float lse = mx + __logf(se);
      int yt = yb[t];
      acc += lg[t * 9 + yt] - lse;
      if (t >= 1) acc += trans[yb[t - 1] * 9 + yt];
    }
  }
#pragma unroll
  for (int off = 32; off >= 1; off >>= 1) acc += __shfl_down(acc, off, 64);

  const int c = (lane < 9) ? lane : 0;
  float score;
  {
    float mx = lg[0];
    for (int cc = 1; cc < 9; ++cc) mx = fmaxf(mx, lg[cc]);
    float se = 0.f;
    for (int cc = 0; cc < 9; ++cc) se += __expf(lg[cc] - mx);
    score = start_t[c] + lg[c] - (mx + __logf(se));
  }
  float tr[9];
#pragma unroll
  for (int cc = 0; cc < 9; ++cc) tr[cc] = trans[cc * 9 + c];
  for (int t = 1; t < L; ++t) {
    const float* lt = lg + t * 9;
    float mx2 = lt[0];
    for (int cc = 1; cc < 9; ++cc) mx2 = fmaxf(mx2, lt[cc]);
    float se2 = 0.f;
    for (int cc = 0; cc < 9; ++cc) se2 += __expf(lt[cc] - mx2);
    float em = lt[c] - (mx2 + __logf(se2));
    float vv[9];
    float mx = -1e30f;
#pragma unroll
    for (int cc = 0; cc < 9; ++cc) {
      float sp = __shfl(score, cc, 64);
      vv[cc] = sp + tr[cc];
      mx = fmaxf(mx, vv[cc]);
    }
    float se = 0.f;
#pragma unroll
    for (int cc = 0; cc < 9; ++cc) se += __expf(vv[cc] - mx);
    score = mx + __logf(se) + em;
  }
  float val = (lane < 9) ? (score + end_t[lane]) : -1e30f;
  float mm = val;
#pragma unroll
  for (int off = 1; off < 64; off <<= 1) mm = fmaxf(mm, __shfl_xor(mm, off, 64));
  float se = (lane < 9) ? __expf(val - mm) : 0.f;
#pragma unroll
  for (int off = 1; off < 64; off <<= 1) se += __shfl_xor(se, off, 64);
  float den = mm + __logf(se);
  if (lane == 0) {
    float num = acc + start_t[yb[0]] + end_t[yb[L - 1]];
    partials[b] = num - den;
  }
}

// ---------------- K4: final reduce ------------------------------------------
__global__ void finalize_kernel(const float* __restrict__ partials, float* __restrict__ out) {
  int l = threadIdx.x;
  float v = partials[l];
#pragma unroll
  for (int off = 32; off >= 1; off >>= 1) v += __shfl_down(v, off, 64);
  if (l == 0) out[0] = -v;
}

extern "C" void kernel_launch(void* const* d_in, const int* in_sizes, int n_in,
                              void* d_out, int out_size, void* d_ws, size_t ws_size,
                              hipStream_t stream) {
  const int*   x     = (const int*)d_in[0];
  const int*   seqln = (const int*)d_in[1];
  const int*   y     = (const int*)d_in[2];
  const float* emb   = (const float*)d_in[3];
  const float* Wih_f = (const float*)d_in[4];
  const float* Whh_f = (const float*)d_in[5];
  const float* b_f   = (const float*)d_in[6];
  const float* Wih_b = (const float*)d_in[7];
  const float* Whh_b = (const float*)d_in[8];
  const float* b_b   = (const float*)d_in[9];
  const float* Wfc   = (const float*)d_in[10];
  const float* st    = (const float*)d_in[11];
  const float* en    = (const float*)d_in[12];
  const float* trans = (const float*)d_in[13];
  float* out = (float*)d_out;

  char* ws = (char*)d_ws;                         // total required ~91.4 MB
  short* WpackX   = (short*)(ws + 0);             // 2,097,152
  short* WpackH   = (short*)(ws + 2097152);       // 4,194,304
  short* WfcPack  = (short*)(ws + 6291456);       //    32,768
  short* xpack    = (short*)(ws + 6324224);       // 16,777,216
  int*   flags    = (int*)  (ws + 23101440);      //     1,024
  float* partials = (float*)(ws + 23102464);      //       256
  float* logits   = (float*)(ws + 23102720);      // 1,179,648
  short* hexch    = (short*)(ws + 24282368);      // 67,108,864 -> end 91,391,232

  pack_weights<<<64, 256, 0, stream>>>(Wih_f, Whh_f, Wih_b, Whh_b, Wfc,
                                       WpackX, WpackH, WfcPack);
  pack_x<<<4096, 256, 0, stream>>>(x, emb, xpack);
  init_state<<<1, 256, 0, stream>>>(flags);
  lstm_step_kernel<<<64, 256, 0, stream>>>((const short8*)xpack, WpackX, WpackH,
                                           hexch, flags, b_f, b_b, seqln);
  emis_kernel<<<256, 256, 0, stream>>>(hexch, WfcPack, logits);
  crf_kernel<<<64, 64, 0, stream>>>(logits, y, seqln, st, en, trans, partials);
  finalize_kernel<<<1, 64, 0, stream>>>(partials, out);
}